// Round 6
// baseline (368.795 us; speedup 1.0000x reference)
//
#include <hip/hip_runtime.h>
#include <hip/hip_bf16.h>

// Problem constants (fixed by the reference file)
#define BB   32      // batch
#define TT   512     // time
#define II   128     // input dim
#define HH   128     // hidden per rnn
#define NR   16      // num independent rnn blocks
#define HTOT 2048    // HH * NR

typedef __attribute__((ext_vector_type(8))) short short8;   // 8 bf16 (4 VGPR) MFMA A/B frag
typedef __attribute__((ext_vector_type(4))) float f32x4;    // MFMA C/D frag

static __device__ __forceinline__ short f2bf(float f) {
    union { __hip_bfloat16 h; short s; } u;
    u.h = __float2bfloat16(f);
    return u.s;
}
static __device__ __forceinline__ float bf2f(unsigned short u) {
    return __uint_as_float(((unsigned int)u) << 16);
}

// ---------------------------------------------------------------------------
// Kernel 1 (unchanged, known good):
// pre = x @ W_ih^T + b_ih + b_hh, bf16 to ws, layout pre[(n*2+g)][t][m][j].
// ---------------------------------------------------------------------------
__global__ __launch_bounds__(512, 2) void msml_pre(
    const float* __restrict__ x,     // (B,T,I)
    const float* __restrict__ Wih,   // (HTOT, II)
    const float* __restrict__ bih,
    const float* __restrict__ bhh,
    unsigned short* __restrict__ pre)
{
    const int mx = blockIdx.x;      // 0..127
    const int n  = blockIdx.y;      // 0..15
    const int tid = threadIdx.x;
    const int w = tid >> 6, l = tid & 63;
    const int q = l >> 4;
    const int r0 = mx * 128;
    const int b  = r0 >> 9;
    const int t0 = r0 & 511;
    const int g  = b >> 4, m = b & 15;

    __shared__ short A[128 * 136];

    {
        const int row = tid >> 2, cb = tid & 3;
        const float4* xs = reinterpret_cast<const float4*>(x + (size_t)(r0 + row) * II + cb * 32);
        short* dst = &A[row * 136 + cb * 32];
#pragma unroll
        for (int i = 0; i < 8; ++i) {
            float4 v = xs[i];
            *reinterpret_cast<short4*>(dst + 4 * i) =
                make_short4(f2bf(v.x), f2bf(v.y), f2bf(v.z), f2bf(v.w));
        }
    }

    const int j = w * 16 + (l & 15);
    short8 bw[4];
    {
        const float* wb = Wih + (size_t)(n * HH + j) * II + q * 8;
#pragma unroll
        for (int kt = 0; kt < 4; ++kt) {
            float4 u0 = *reinterpret_cast<const float4*>(wb + kt * 32);
            float4 u1 = *reinterpret_cast<const float4*>(wb + kt * 32 + 4);
            short8 s;
            s[0] = f2bf(u0.x); s[1] = f2bf(u0.y); s[2] = f2bf(u0.z); s[3] = f2bf(u0.w);
            s[4] = f2bf(u1.x); s[5] = f2bf(u1.y); s[6] = f2bf(u1.z); s[7] = f2bf(u1.w);
            bw[kt] = s;
        }
    }
    const float bias = bih[n * HH + j] + bhh[n * HH + j];
    __syncthreads();

    const size_t ng = (size_t)(n * 2 + g);
#pragma unroll
    for (int mt = 0; mt < 8; ++mt) {
        const short* ap = &A[(mt * 16 + (l & 15)) * 136 + q * 8];
        f32x4 acc = {0.f, 0.f, 0.f, 0.f};
#pragma unroll
        for (int kt = 0; kt < 4; ++kt) {
            short8 a = *reinterpret_cast<const short8*>(ap + kt * 32);
            acc = __builtin_amdgcn_mfma_f32_16x16x32_bf16(a, bw[kt], acc, 0, 0, 0);
        }
#pragma unroll
        for (int r = 0; r < 4; ++r) {
            const int t = t0 + mt * 16 + q * 4 + r;
            pre[((ng * TT + t) * 16 + m) * 128 + j] = (unsigned short)f2bf(acc[r] + bias);
        }
    }
}

// ---------------------------------------------------------------------------
// Kernel 2: 8-wave recurrence. One WG per (n, batch-group g of 16): 32 WGs.
// Wave w owns output tile j = w*16..w*16+15 for all 16 batches.
//   A = Wn rows (stationary regs), B = H^T from LDS (b128), C seeded with pre.
// Barrier is the verified m201 idiom: lgkmcnt(0)-only wait + raw s_barrier,
// NO memory clobber -> outstanding global loads/stores float across it
// (no vmcnt drain on the critical path). pre prefetched 3 steps ahead so
// HBM load latency AND in-order store retirement are both covered.
// ---------------------------------------------------------------------------
__global__ __launch_bounds__(512, 2) void msml_recur8w(
    const float* __restrict__ Whh,            // (HTOT, HTOT)
    const unsigned short* __restrict__ pre,   // bf16 (NR*2, TT, 16, 128)
    float* __restrict__ out)
{
    const int n = blockIdx.x;   // 0..15
    const int g = blockIdx.y;   // 0..1
    const int tid = threadIdx.x;
    const int w = tid >> 6;     // wave = output tile
    const int l = tid & 63;
    const int m = l & 15;       // batch (B col / D col); also A row-within-tile
    const int q = l >> 4;       // 0..3

    __shared__ short Hs[2][16 * 136];   // H[batch][j] bf16, row stride 136

    // ---- stationary A-frags: wf[kt] = Wn[w*16 + m][kt*32 + q*8 .. +7] ----
    short8 wf[4];
#pragma unroll
    for (int kt = 0; kt < 4; ++kt) {
        const float* wp = Whh + (size_t)(n * HH + w * 16 + m) * HTOT + n * HH + kt * 32 + q * 8;
        float4 u0 = *reinterpret_cast<const float4*>(wp);
        float4 u1 = *reinterpret_cast<const float4*>(wp + 4);
        short8 s;
        s[0] = f2bf(u0.x); s[1] = f2bf(u0.y); s[2] = f2bf(u0.z); s[3] = f2bf(u0.w);
        s[4] = f2bf(u1.x); s[5] = f2bf(u1.y); s[6] = f2bf(u1.z); s[7] = f2bf(u1.w);
        wf[kt] = s;
    }

    const short8 zs = {0, 0, 0, 0, 0, 0, 0, 0};
    const f32x4 zero4 = {0.f, 0.f, 0.f, 0.f};

    // per-lane pre address: batch m, cols w*16 + q*4 .. +3 (b64 = 4 bf16)
    const unsigned short* pb = pre + (size_t)(n * 2 + g) * TT * 2048 + m * 128 + w * 16 + q * 4;
    // output base: row b = g*16+m, col n*128 + w*16 + q*4
    float* ob = out + (size_t)(g * 16 + m) * TT * HTOT + n * HH + w * 16 + q * 4;

    // prologue: 3-deep pre prefetch; h_{-1} = 0
    ushort4 pA = *reinterpret_cast<const ushort4*>(pb);
    ushort4 pB = *reinterpret_cast<const ushort4*>(pb + 2048);
    ushort4 pC = *reinterpret_cast<const ushort4*>(pb + 2 * 2048);
    short8 hf[4];
#pragma unroll
    for (int kt = 0; kt < 4; ++kt) hf[kt] = zs;

    for (int t = 0; t < TT; ++t) {
        const bool last = (t == TT - 1);

        // ---- issue pre load for t+3 (3 loads in flight) ----
        const int tn = (t + 3 < TT) ? t + 3 : TT - 1;
        ushort4 pD = *reinterpret_cast<const ushort4*>(pb + (size_t)tn * 2048);

        // ---- two 2-deep MFMA chains; chain0 seeded with pre[t] ----
        f32x4 c0;
        c0[0] = bf2f(pA.x); c0[1] = bf2f(pA.y);
        c0[2] = bf2f(pA.z); c0[3] = bf2f(pA.w);
        f32x4 a0 = __builtin_amdgcn_mfma_f32_16x16x32_bf16(wf[0], hf[0], c0, 0, 0, 0);
        f32x4 a1 = __builtin_amdgcn_mfma_f32_16x16x32_bf16(wf[2], hf[2], zero4, 0, 0, 0);
        a0 = __builtin_amdgcn_mfma_f32_16x16x32_bf16(wf[1], hf[1], a0, 0, 0, 0);
        a1 = __builtin_amdgcn_mfma_f32_16x16x32_bf16(wf[3], hf[3], a1, 0, 0, 0);

        // ---- epilogue: relu, pack bf16 -> LDS b64 ----
        float h0 = fmaxf(a0[0] + a1[0], 0.f);
        float h1 = fmaxf(a0[1] + a1[1], 0.f);
        float h2 = fmaxf(a0[2] + a1[2], 0.f);
        float h3 = fmaxf(a0[3] + a1[3], 0.f);

        unsigned int p0 = (unsigned int)(unsigned short)f2bf(h0) |
                          ((unsigned int)(unsigned short)f2bf(h1) << 16);
        unsigned int p1 = (unsigned int)(unsigned short)f2bf(h2) |
                          ((unsigned int)(unsigned short)f2bf(h3) << 16);
        *reinterpret_cast<uint2*>(&Hs[t & 1][m * 136 + w * 16 + q * 4]) = make_uint2(p0, p1);

        if (last) {
            *reinterpret_cast<float4*>(ob + (size_t)t * HTOT) = make_float4(h0, h1, h2, h3);
            *reinterpret_cast<float4*>(out + (size_t)BB * TT * HTOT +
                                       (size_t)(g * 16 + m) * HTOT + n * HH + w * 16 + q * 4) =
                make_float4(h0, h1, h2, h3);
            break;
        }

        // ---- LDS-visibility barrier, no vmcnt drain (m201 idiom) ----
        __builtin_amdgcn_sched_barrier(0);
        asm volatile("s_waitcnt lgkmcnt(0)");   // my ds_write complete (no mem clobber!)
        __builtin_amdgcn_s_barrier();           // all waves' writes complete
        __builtin_amdgcn_sched_barrier(0);

        // ---- read full H_t for next step (compiler adds fine-grained waits) ----
#pragma unroll
        for (int kt = 0; kt < 4; ++kt)
            hf[kt] = *reinterpret_cast<const short8*>(&Hs[t & 1][m * 136 + kt * 32 + q * 8]);

        // ---- output store off the critical path ----
        *reinterpret_cast<float4*>(ob + (size_t)t * HTOT) = make_float4(h0, h1, h2, h3);

        pA = pB; pB = pC; pC = pD;
    }
}

// ---------------------------------------------------------------------------
// Fallback (round-2 kernel, known-good): used if ws_size is too small.
// ---------------------------------------------------------------------------
__global__ __launch_bounds__(512, 4) void msml_fused2(
    const float* __restrict__ x,
    const float* __restrict__ Wih,
    const float* __restrict__ Whh,
    const float* __restrict__ bih,
    const float* __restrict__ bhh,
    float* __restrict__ out)
{
    const int n    = blockIdx.x;
    const int b    = blockIdx.y;
    const int tid  = threadIdx.x;
    const int wave = tid >> 6;
    const int lane = tid & 63;
    const int s    = lane >> 4;
    const int j    = wave * 16 + (lane & 15);
    const int row  = n * HH + j;

    float wih[32], whh[32];
    {
        const float4* wi4 = reinterpret_cast<const float4*>(Wih + (size_t)row * II);
        const float4* wh4 = reinterpret_cast<const float4*>(Whh + (size_t)row * HTOT + n * HH);
#pragma unroll
        for (int k = 0; k < 8; ++k) {
            float4 a = wi4[4 * k + s];
            wih[4*k+0] = a.x; wih[4*k+1] = a.y; wih[4*k+2] = a.z; wih[4*k+3] = a.w;
            float4 c = wh4[4 * k + s];
            whh[4*k+0] = c.x; whh[4*k+1] = c.y; whh[4*k+2] = c.z; whh[4*k+3] = c.w;
        }
    }
    const float bias0 = (s == 0) ? (bih[row] + bhh[row]) : 0.0f;

    __shared__ float hs[2][HH];
    if (tid < HH) hs[0][tid] = 0.0f;

    const float* xrow = x + (size_t)b * TT * II;
    float* orow = out + (size_t)b * TT * HTOT + (size_t)n * HH + j;

    float accx;
    {
        const float4* xv = reinterpret_cast<const float4*>(xrow);
        float a0 = bias0, a1 = 0.f, a2 = 0.f, a3 = 0.f;
#pragma unroll
        for (int k = 0; k < 8; ++k) {
            float4 v = xv[4 * k + s];
            a0 += wih[4*k+0] * v.x; a1 += wih[4*k+1] * v.y;
            a2 += wih[4*k+2] * v.z; a3 += wih[4*k+3] * v.w;
        }
        accx = (a0 + a1) + (a2 + a3);
    }
    __syncthreads();

    float hn = 0.0f;
    int buf = 0;
    for (int t = 0; t < TT; ++t) {
        float4 xn[8];
        if (t + 1 < TT) {
            const float4* xv = reinterpret_cast<const float4*>(xrow + (size_t)(t + 1) * II);
#pragma unroll
            for (int k = 0; k < 8; ++k) xn[k] = xv[4 * k + s];
        }
        const float4* hv = reinterpret_cast<const float4*>(hs[buf]);
        float a0 = accx, a1 = 0.f, a2 = 0.f, a3 = 0.f;
#pragma unroll
        for (int k = 0; k < 8; ++k) {
            float4 v = hv[4 * k + s];
            a0 += whh[4*k+0] * v.x; a1 += whh[4*k+1] * v.y;
            a2 += whh[4*k+2] * v.z; a3 += whh[4*k+3] * v.w;
        }
        float sum = (a0 + a1) + (a2 + a3);
        sum += __shfl_xor(sum, 16);
        sum += __shfl_xor(sum, 32);
        hn = fmaxf(sum, 0.0f);

        if (s == 0) {
            orow[(size_t)t * HTOT] = hn;
            hs[buf ^ 1][j] = hn;
        }
        {
            float b0 = bias0, b1 = 0.f, b2 = 0.f, b3 = 0.f;
#pragma unroll
            for (int k = 0; k < 8; ++k) {
                b0 += wih[4*k+0] * xn[k].x; b1 += wih[4*k+1] * xn[k].y;
                b2 += wih[4*k+2] * xn[k].z; b3 += wih[4*k+3] * xn[k].w;
            }
            accx = (b0 + b1) + (b2 + b3);
        }
        buf ^= 1;
        __syncthreads();
    }

    if (s == 0)
        out[(size_t)BB * TT * HTOT + (size_t)b * HTOT + row] = hn;
}

extern "C" void kernel_launch(void* const* d_in, const int* in_sizes, int n_in,
                              void* d_out, int out_size, void* d_ws, size_t ws_size,
                              hipStream_t stream) {
    const float* x   = (const float*)d_in[0];
    const float* Wih = (const float*)d_in[1];
    const float* Whh = (const float*)d_in[2];
    const float* bih = (const float*)d_in[3];
    const float* bhh = (const float*)d_in[4];
    float* out = (float*)d_out;

    const size_t pre_bytes = (size_t)NR * 2 * TT * 16 * 128 * sizeof(unsigned short); // 64 MiB

    if (ws_size >= pre_bytes && d_ws != nullptr) {
        unsigned short* pre = (unsigned short*)d_ws;
        msml_pre<<<dim3(128, NR), 512, 0, stream>>>(x, Wih, bih, bhh, pre);
        msml_recur8w<<<dim3(NR, 2), 512, 0, stream>>>(Whh, pre, out);
    } else {
        msml_fused2<<<dim3(NR, BB), 512, 0, stream>>>(x, Wih, Whh, bih, bhh, out);
    }
}

// Round 7
// 204.846 us; speedup vs baseline: 1.8004x; 1.8004x over previous
//
#include <hip/hip_runtime.h>
#include <hip/hip_bf16.h>

// Problem constants (fixed by the reference file)
#define BB   32      // batch
#define TT   512     // time
#define II   128     // input dim
#define HH   128     // hidden per rnn
#define NR   16      // num independent rnn blocks
#define HTOT 2048    // HH * NR

typedef __attribute__((ext_vector_type(8))) short short8;   // 8 bf16 (4 VGPR) MFMA A/B frag
typedef __attribute__((ext_vector_type(4))) float f32x4;    // MFMA C/D frag

static __device__ __forceinline__ short f2bf(float f) {
    union { __hip_bfloat16 h; short s; } u;
    u.h = __float2bfloat16(f);
    return u.s;
}
static __device__ __forceinline__ float bf2f(unsigned short u) {
    return __uint_as_float(((unsigned int)u) << 16);
}

// ---------------------------------------------------------------------------
// Kernel 1 (unchanged, known good):
// pre = x @ W_ih^T + b_ih + b_hh, bf16 to ws, layout pre[(n*2+g)][t][m][j].
// ---------------------------------------------------------------------------
__global__ __launch_bounds__(512, 2) void msml_pre(
    const float* __restrict__ x,     // (B,T,I)
    const float* __restrict__ Wih,   // (HTOT, II)
    const float* __restrict__ bih,
    const float* __restrict__ bhh,
    unsigned short* __restrict__ pre)
{
    const int mx = blockIdx.x;      // 0..127
    const int n  = blockIdx.y;      // 0..15
    const int tid = threadIdx.x;
    const int w = tid >> 6, l = tid & 63;
    const int q = l >> 4;
    const int r0 = mx * 128;
    const int b  = r0 >> 9;
    const int t0 = r0 & 511;
    const int g  = b >> 4, m = b & 15;

    __shared__ short A[128 * 136];

    {
        const int row = tid >> 2, cb = tid & 3;
        const float4* xs = reinterpret_cast<const float4*>(x + (size_t)(r0 + row) * II + cb * 32);
        short* dst = &A[row * 136 + cb * 32];
#pragma unroll
        for (int i = 0; i < 8; ++i) {
            float4 v = xs[i];
            *reinterpret_cast<short4*>(dst + 4 * i) =
                make_short4(f2bf(v.x), f2bf(v.y), f2bf(v.z), f2bf(v.w));
        }
    }

    const int j = w * 16 + (l & 15);
    short8 bw[4];
    {
        const float* wb = Wih + (size_t)(n * HH + j) * II + q * 8;
#pragma unroll
        for (int kt = 0; kt < 4; ++kt) {
            float4 u0 = *reinterpret_cast<const float4*>(wb + kt * 32);
            float4 u1 = *reinterpret_cast<const float4*>(wb + kt * 32 + 4);
            short8 s;
            s[0] = f2bf(u0.x); s[1] = f2bf(u0.y); s[2] = f2bf(u0.z); s[3] = f2bf(u0.w);
            s[4] = f2bf(u1.x); s[5] = f2bf(u1.y); s[6] = f2bf(u1.z); s[7] = f2bf(u1.w);
            bw[kt] = s;
        }
    }
    const float bias = bih[n * HH + j] + bhh[n * HH + j];
    __syncthreads();

    const size_t ng = (size_t)(n * 2 + g);
#pragma unroll
    for (int mt = 0; mt < 8; ++mt) {
        const short* ap = &A[(mt * 16 + (l & 15)) * 136 + q * 8];
        f32x4 acc = {0.f, 0.f, 0.f, 0.f};
#pragma unroll
        for (int kt = 0; kt < 4; ++kt) {
            short8 a = *reinterpret_cast<const short8*>(ap + kt * 32);
            acc = __builtin_amdgcn_mfma_f32_16x16x32_bf16(a, bw[kt], acc, 0, 0, 0);
        }
#pragma unroll
        for (int r = 0; r < 4; ++r) {
            const int t = t0 + mt * 16 + q * 4 + r;
            pre[((ng * TT + t) * 16 + m) * 128 + j] = (unsigned short)f2bf(acc[r] + bias);
        }
    }
}

// ---------------------------------------------------------------------------
// Kernel 2: EXACT round-3 recurrence (best measured: 172us) with ONE change:
// the per-step __syncthreads() (which drains vmcnt(0), exposing the pre
// prefetch + store-ack latency every step) is replaced by an LDS-only
// barrier: lgkmcnt(0) wait + raw s_barrier, bracketed by sched_barrier(0)
// so ds ops cannot be scheduled across it. No "memory" clobber -> global
// loads/stores stay in flight across the barrier.
// ---------------------------------------------------------------------------
__global__ __launch_bounds__(512, 2) void msml_recur(
    const float* __restrict__ Whh,            // (HTOT, HTOT)
    const unsigned short* __restrict__ pre,   // bf16 (NR*2, TT, 16, 128)
    float* __restrict__ out)
{
    const int n = blockIdx.x;   // 0..15
    const int g = blockIdx.y;   // 0..1
    const int tid = threadIdx.x;
    const int w = tid >> 6, l = tid & 63;
    const int q = l >> 4;               // 0..3
    const int j = w * 16 + (l & 15);    // output col 0..127

    __shared__ short Hl[2][16 * 136];

    // ---- Wn^T B-fragments (diag block of Whh), fp32 -> bf16, regs forever ----
    short8 bw[4];
#pragma unroll
    for (int kt = 0; kt < 4; ++kt) {
        const float* wb = Whh + (size_t)(n * HH + j) * HTOT + n * HH + kt * 32 + q * 8;
        float4 u0 = *reinterpret_cast<const float4*>(wb);
        float4 u1 = *reinterpret_cast<const float4*>(wb + 4);
        short8 s;
        s[0] = f2bf(u0.x); s[1] = f2bf(u0.y); s[2] = f2bf(u0.z); s[3] = f2bf(u0.w);
        s[4] = f2bf(u1.x); s[5] = f2bf(u1.y); s[6] = f2bf(u1.z); s[7] = f2bf(u1.w);
        bw[kt] = s;
    }

    // zero H buffer 0 (h_{-1} = 0)
    for (int i = tid; i < 16 * 136; i += 512) Hl[0][i] = 0;

    // pre base for this thread: rows m = q*4 + r, col j
    const unsigned short* pb = pre + ((size_t)(n * 2 + g) * TT) * 2048 + (q * 4) * 128 + j;
    unsigned short pA0, pA1, pA2, pA3, pB0, pB1, pB2, pB3;
    { const unsigned short* pp = pb;        pA0 = pp[0]; pA1 = pp[128]; pA2 = pp[256]; pA3 = pp[384]; }
    { const unsigned short* pp = pb + 2048; pB0 = pp[0]; pB1 = pp[128]; pB2 = pp[256]; pB3 = pp[384]; }

    const size_t MS = (size_t)TT * HTOT;   // out stride per batch row
    float* ob = out + (size_t)(g * 16 + q * 4) * MS + n * HH + j;

    __syncthreads();   // Hl[0] zeros visible (startup only)

#define RSTEP(HRD, HWR, P0, P1, P2, P3, TCUR)                                      \
    {                                                                              \
        const short* hp = &HRD[(l & 15) * 136 + q * 8];                            \
        f32x4 acc = {0.f, 0.f, 0.f, 0.f};                                          \
        _Pragma("unroll")                                                          \
        for (int kt = 0; kt < 4; ++kt) {                                           \
            short8 a = *reinterpret_cast<const short8*>(hp + kt * 32);             \
            acc = __builtin_amdgcn_mfma_f32_16x16x32_bf16(a, bw[kt], acc, 0, 0, 0);\
        }                                                                          \
        float h0 = fmaxf(acc[0] + bf2f(P0), 0.f);                                  \
        float h1 = fmaxf(acc[1] + bf2f(P1), 0.f);                                  \
        float h2 = fmaxf(acc[2] + bf2f(P2), 0.f);                                  \
        float h3 = fmaxf(acc[3] + bf2f(P3), 0.f);                                  \
        { int tn = (TCUR) + 2 < TT ? (TCUR) + 2 : TT - 1;                          \
          const unsigned short* pp = pb + (size_t)tn * 2048;                       \
          P0 = pp[0]; P1 = pp[128]; P2 = pp[256]; P3 = pp[384]; }                  \
        float* oo = ob + (size_t)(TCUR) * HTOT;                                    \
        oo[0] = h0; oo[MS] = h1; oo[2 * MS] = h2; oo[3 * MS] = h3;                 \
        HWR[(q * 4 + 0) * 136 + j] = f2bf(h0);                                     \
        HWR[(q * 4 + 1) * 136 + j] = f2bf(h1);                                     \
        HWR[(q * 4 + 2) * 136 + j] = f2bf(h2);                                     \
        HWR[(q * 4 + 3) * 136 + j] = f2bf(h3);                                     \
        if ((TCUR) == TT - 1) {                                                    \
            float* hh = out + (size_t)BB * TT * HTOT                               \
                        + (size_t)(g * 16 + q * 4) * HTOT + n * HH + j;            \
            hh[0] = h0; hh[HTOT] = h1; hh[2 * HTOT] = h2; hh[3 * HTOT] = h3;       \
        }                                                                          \
        __builtin_amdgcn_sched_barrier(0);                                         \
        asm volatile("s_waitcnt lgkmcnt(0)");                                      \
        __builtin_amdgcn_s_barrier();                                              \
        __builtin_amdgcn_sched_barrier(0);                                         \
    }

    short* hb0 = &Hl[0][0];
    short* hb1 = &Hl[1][0];
    for (int t = 0; t < TT; t += 2) {
        RSTEP(hb0, hb1, pA0, pA1, pA2, pA3, t)
        RSTEP(hb1, hb0, pB0, pB1, pB2, pB3, t + 1)
    }
#undef RSTEP
}

// ---------------------------------------------------------------------------
// Fallback (round-2 kernel, known-good): used if ws_size is too small.
// ---------------------------------------------------------------------------
__global__ __launch_bounds__(512, 4) void msml_fused2(
    const float* __restrict__ x,
    const float* __restrict__ Wih,
    const float* __restrict__ Whh,
    const float* __restrict__ bih,
    const float* __restrict__ bhh,
    float* __restrict__ out)
{
    const int n    = blockIdx.x;
    const int b    = blockIdx.y;
    const int tid  = threadIdx.x;
    const int wave = tid >> 6;
    const int lane = tid & 63;
    const int s    = lane >> 4;
    const int j    = wave * 16 + (lane & 15);
    const int row  = n * HH + j;

    float wih[32], whh[32];
    {
        const float4* wi4 = reinterpret_cast<const float4*>(Wih + (size_t)row * II);
        const float4* wh4 = reinterpret_cast<const float4*>(Whh + (size_t)row * HTOT + n * HH);
#pragma unroll
        for (int k = 0; k < 8; ++k) {
            float4 a = wi4[4 * k + s];
            wih[4*k+0] = a.x; wih[4*k+1] = a.y; wih[4*k+2] = a.z; wih[4*k+3] = a.w;
            float4 c = wh4[4 * k + s];
            whh[4*k+0] = c.x; whh[4*k+1] = c.y; whh[4*k+2] = c.z; whh[4*k+3] = c.w;
        }
    }
    const float bias0 = (s == 0) ? (bih[row] + bhh[row]) : 0.0f;

    __shared__ float hs[2][HH];
    if (tid < HH) hs[0][tid] = 0.0f;

    const float* xrow = x + (size_t)b * TT * II;
    float* orow = out + (size_t)b * TT * HTOT + (size_t)n * HH + j;

    float accx;
    {
        const float4* xv = reinterpret_cast<const float4*>(xrow);
        float a0 = bias0, a1 = 0.f, a2 = 0.f, a3 = 0.f;
#pragma unroll
        for (int k = 0; k < 8; ++k) {
            float4 v = xv[4 * k + s];
            a0 += wih[4*k+0] * v.x; a1 += wih[4*k+1] * v.y;
            a2 += wih[4*k+2] * v.z; a3 += wih[4*k+3] * v.w;
        }
        accx = (a0 + a1) + (a2 + a3);
    }
    __syncthreads();

    float hn = 0.0f;
    int buf = 0;
    for (int t = 0; t < TT; ++t) {
        float4 xn[8];
        if (t + 1 < TT) {
            const float4* xv = reinterpret_cast<const float4*>(xrow + (size_t)(t + 1) * II);
#pragma unroll
            for (int k = 0; k < 8; ++k) xn[k] = xv[4 * k + s];
        }
        const float4* hv = reinterpret_cast<const float4*>(hs[buf]);
        float a0 = accx, a1 = 0.f, a2 = 0.f, a3 = 0.f;
#pragma unroll
        for (int k = 0; k < 8; ++k) {
            float4 v = hv[4 * k + s];
            a0 += whh[4*k+0] * v.x; a1 += whh[4*k+1] * v.y;
            a2 += whh[4*k+2] * v.z; a3 += whh[4*k+3] * v.w;
        }
        float sum = (a0 + a1) + (a2 + a3);
        sum += __shfl_xor(sum, 16);
        sum += __shfl_xor(sum, 32);
        hn = fmaxf(sum, 0.0f);

        if (s == 0) {
            orow[(size_t)t * HTOT] = hn;
            hs[buf ^ 1][j] = hn;
        }
        {
            float b0 = bias0, b1 = 0.f, b2 = 0.f, b3 = 0.f;
#pragma unroll
            for (int k = 0; k < 8; ++k) {
                b0 += wih[4*k+0] * xn[k].x; b1 += wih[4*k+1] * xn[k].y;
                b2 += wih[4*k+2] * xn[k].z; b3 += wih[4*k+3] * xn[k].w;
            }
            accx = (b0 + b1) + (b2 + b3);
        }
        buf ^= 1;
        __syncthreads();
    }

    if (s == 0)
        out[(size_t)BB * TT * HTOT + (size_t)b * HTOT + row] = hn;
}

extern "C" void kernel_launch(void* const* d_in, const int* in_sizes, int n_in,
                              void* d_out, int out_size, void* d_ws, size_t ws_size,
                              hipStream_t stream) {
    const float* x   = (const float*)d_in[0];
    const float* Wih = (const float*)d_in[1];
    const float* Whh = (const float*)d_in[2];
    const float* bih = (const float*)d_in[3];
    const float* bhh = (const float*)d_in[4];
    float* out = (float*)d_out;

    const size_t pre_bytes = (size_t)NR * 2 * TT * 16 * 128 * sizeof(unsigned short); // 64 MiB

    if (ws_size >= pre_bytes && d_ws != nullptr) {
        unsigned short* pre = (unsigned short*)d_ws;
        msml_pre<<<dim3(128, NR), 512, 0, stream>>>(x, Wih, bih, bhh, pre);
        msml_recur<<<dim3(NR, 2), 512, 0, stream>>>(Whh, pre, out);
    } else {
        msml_fused2<<<dim3(NR, BB), 512, 0, stream>>>(x, Wih, Whh, bih, bhh, out);
    }
}